// Round 1
// 298.688 us; speedup vs baseline: 1.0489x; 1.0489x over previous
//
#include <hip/hip_runtime.h>

#define N_NODES 50000
#define N_EDGES 320000
#define IN_FEAT 128
#define HIDDEN  256
#define NCLS    40
#define BN_EPS  1e-5f

#define SCAN_B  256
#define SCAN_NB ((N_NODES + SCAN_B - 1) / SCAN_B)   // 196
#define GNB     (N_NODES / 16)                      // 3125 blocks, 16 nodes each

// prep kernel partition
#define PREP_HIST_NB  (N_EDGES / 256)               // 1250
#define PREP_CVT_NB   (N_NODES * IN_FEAT / 8 / 256) // 3125
#define PREP_PACK_NB  54                            // 216 wave-units / 4

typedef __attribute__((ext_vector_type(8))) _Float16 f16x8;
typedef __attribute__((ext_vector_type(2))) _Float16 f16x2;
typedef __attribute__((ext_vector_type(4))) float f32x4;

__device__ __forceinline__ f16x2 pkmax0(f16x2 a) {
    return __builtin_elementwise_max(a, (f16x2)(_Float16)0.f);
}

__device__ __forceinline__ void packB_unit(const float* __restrict__ W,
                                           _Float16* __restrict__ Bp,
                                           int nt, int kt, int nkt, int M, int lane) {
    const int n = nt * 16 + (lane & 15);
    const int kb = kt * 32 + (lane >> 4) * 8;
    _Float16* dst = Bp + (((size_t)nt * nkt + kt) * 64 + lane) * 8;
#pragma unroll
    for (int j = 0; j < 8; j++)
        dst[j] = (n < M) ? (_Float16)W[(size_t)(kb + j) * M + n] : (_Float16)0.f;
}

// ---------------- merged prep: hist + x cast + W packs ----------------
__global__ __launch_bounds__(256) void k_prep(const int* __restrict__ e_dst,
                                              int* __restrict__ counts,
                                              const float* __restrict__ x,
                                              _Float16* __restrict__ Xh,
                                              const float* __restrict__ W1,
                                              const float* __restrict__ W2,
                                              const float* __restrict__ W3,
                                              _Float16* __restrict__ W1p,
                                              _Float16* __restrict__ W2p,
                                              _Float16* __restrict__ W3p) {
    const int b = blockIdx.x;
    const int tid = threadIdx.x;
    if (b < PREP_HIST_NB) {
        const int e = b * 256 + tid;                  // 1250*256 == N_EDGES
        atomicAdd(&counts[e_dst[e]], 1);
    } else if (b < PREP_HIST_NB + PREP_CVT_NB) {
        const int i = (b - PREP_HIST_NB) * 256 + tid; // exact cover
        float4 a = *(const float4*)(x + (size_t)i * 8);
        float4 c = *(const float4*)(x + (size_t)i * 8 + 4);
        f16x8 o = {(_Float16)a.x, (_Float16)a.y, (_Float16)a.z, (_Float16)a.w,
                   (_Float16)c.x, (_Float16)c.y, (_Float16)c.z, (_Float16)c.w};
        *(f16x8*)&Xh[(size_t)i * 8] = o;
    } else {
        const int wave = tid >> 6, lane = tid & 63;
        const int u = (b - PREP_HIST_NB - PREP_CVT_NB) * 4 + wave;  // 0..215
        if (u < 64) {
            packB_unit(W1, W1p, u >> 2, u & 3, 4, HIDDEN, lane);
        } else if (u < 192) {
            const int v = u - 64;
            packB_unit(W2, W2p, v >> 3, v & 7, 8, HIDDEN, lane);
        } else {
            const int v = u - 192;
            packB_unit(W3, W3p, v >> 3, v & 7, 8, NCLS, lane);
        }
    }
}

// ---------------- CSR scan ----------------
__global__ __launch_bounds__(SCAN_B) void k_scan_local(const int* __restrict__ counts,
                                                       int* __restrict__ rowp,
                                                       int* __restrict__ partials) {
    __shared__ int s[SCAN_B];
    const int tid = threadIdx.x;
    const int i = blockIdx.x * SCAN_B + tid;
    int v = (i < N_NODES) ? counts[i] : 0;
    s[tid] = v;
    __syncthreads();
    for (int off = 1; off < SCAN_B; off <<= 1) {
        int t = (tid >= off) ? s[tid - off] : 0;
        __syncthreads();
        s[tid] += t;
        __syncthreads();
    }
    if (i < N_NODES) rowp[i] = s[tid] - v;
    if (tid == SCAN_B - 1) partials[blockIdx.x] = s[SCAN_B - 1];
}

__global__ __launch_bounds__(SCAN_B) void k_scan_add(int* __restrict__ rowp,
                                                     int* __restrict__ cursor,
                                                     const int* __restrict__ partials,
                                                     const int* __restrict__ counts,
                                                     float* __restrict__ dinv) {
    __shared__ int s[SCAN_B];
    const int tid = threadIdx.x;
    const int b = blockIdx.x;
    int v = (tid < b) ? partials[tid] : 0;
    s[tid] = v;
    __syncthreads();
    for (int off = SCAN_B / 2; off > 0; off >>= 1) {
        if (tid < off) s[tid] += s[tid + off];
        __syncthreads();
    }
    const int offset = s[0];
    const int i = b * SCAN_B + tid;
    if (i < N_NODES) {
        int r = rowp[i] + offset;
        rowp[i] = r;
        cursor[i] = r;
        dinv[i] = rsqrtf(1.0f + (float)counts[i]);
    }
    if (b == 0 && tid == 0) rowp[N_NODES] = N_EDGES;
}

// scatter: packed (src, wnorm) per edge -> single 8B random store
__global__ void k_scatter(const int* __restrict__ src, const int* __restrict__ dst,
                          int* __restrict__ cursor, const float* __restrict__ dinv,
                          int2* __restrict__ edat) {
    int e = blockIdx.x * blockDim.x + threadIdx.x;
    if (e < N_EDGES) {
        int d = dst[e], s = src[e];
        int p = atomicAdd(&cursor[d], 1);
        int2 v; v.x = s; v.y = __float_as_int(dinv[s] * dinv[d]);
        edat[p] = v;
    }
}

// ---------------- fused layer: parallel-row gather -> LDS -> MFMA f16 --------
// Block: 16 nodes. Wave handles 4 nodes IN PARALLEL via 16-lane subgroups
// (latency fix: old code walked its 4 rows sequentially = ~26 dependent
// memory round-trips/wave; now: one coalesced (src,w) preload + shfl
// broadcast, all rows' gathers issued back-to-back).
template <int KIN, bool BN>
__global__ __launch_bounds__(256, 4) void k_fused(const _Float16* __restrict__ Xin,
                                               const int* __restrict__ rowp,
                                               const int2* __restrict__ edat,
                                               const float* __restrict__ dinv,
                                               const float* __restrict__ scale,
                                               const float* __restrict__ shift,
                                               const _Float16* __restrict__ Bp,
                                               const float* __restrict__ bias,
                                               _Float16* __restrict__ C,
                                               float* __restrict__ bnp) {
    constexpr int nkt = KIN / 32;
    constexpr int LROW = KIN + 8;
    constexpr int RW8 = KIN / 8;                 // f16x8 words per feature row
    __shared__ __align__(16) _Float16 At[16 * LROW];
    const int wave = threadIdx.x >> 6;
    const int lane = threadIdx.x & 63;
    const int sub  = lane >> 4;                  // node slot within wave
    const int t    = lane & 15;                  // lane within subgroup
    const int sb   = lane & 48;                  // subgroup base lane
    const int node = blockIdx.x * 16 + wave * 4 + sub;

    const int e0 = rowp[node];
    const int e1 = rowp[node + 1];
    const int deg = e1 - e0;
    // coalesced preload of up to 16 (src, w) pairs into the subgroup's lanes
    int   pidx = 0;
    float pw   = 0.f;
    if (t < deg) {
        const int2 e = edat[e0 + t];
        pidx = e.x;
        pw = __int_as_float(e.y);
    }
    const float dd = dinv[node];
    const f16x2 sw2 = (f16x2)(_Float16)(dd * dd);

    const f16x8* __restrict__ Xr = (const f16x8*)Xin;
    union U8 { f16x8 v; f16x2 h[4]; };

    if constexpr (KIN == 128) {
        U8 a;
        {
            U8 r; r.v = Xr[(size_t)node * RW8 + t];
#pragma unroll
            for (int p = 0; p < 4; p++) a.h[p] = sw2 * r.h[p];
        }
        auto edge = [&](int j) {
            const int   idx = __shfl(pidx, sb + j);
            const float wv  = __shfl(pw,  sb + j);
            if (j < deg) {
                const f16x2 w2 = (f16x2)(_Float16)wv;
                U8 r; r.v = Xr[(size_t)idx * RW8 + t];
#pragma unroll
                for (int p = 0; p < 4; p++) a.h[p] = w2 * r.h[p] + a.h[p];
            }
        };
#pragma unroll
        for (int j = 0; j < 8; j++) edge(j);
        if (__any(deg > 8)) {
#pragma unroll
            for (int j = 8; j < 16; j++) edge(j);
            if (__any(deg > 16)) {
                for (int j = 16; j < deg; j++) {
                    const int2 ed = edat[e0 + j];
                    const f16x2 w2 = (f16x2)(_Float16)__int_as_float(ed.y);
                    U8 r; r.v = Xr[(size_t)ed.x * RW8 + t];
#pragma unroll
                    for (int p = 0; p < 4; p++) a.h[p] = w2 * r.h[p] + a.h[p];
                }
            }
        }
        *(f16x8*)&At[(wave * 4 + sub) * LROW + t * 8] = a.v;
    } else {
        // lane covers feats [t*8, t*8+8) and [128+t*8, 128+t*8+8)
        f16x2 sc[8], sh[8];
        if constexpr (BN) {
#pragma unroll
            for (int p = 0; p < 4; p++) {
                const int f0 = t * 8 + 2 * p;
                sc[p]     = f16x2{(_Float16)scale[f0], (_Float16)scale[f0 + 1]};
                sh[p]     = f16x2{(_Float16)shift[f0], (_Float16)shift[f0 + 1]};
                sc[4 + p] = f16x2{(_Float16)scale[128 + f0], (_Float16)scale[128 + f0 + 1]};
                sh[4 + p] = f16x2{(_Float16)shift[128 + f0], (_Float16)shift[128 + f0 + 1]};
            }
        }
        U8 a0, a1;
        {
            U8 r0, r1;
            r0.v = Xr[(size_t)node * RW8 + t];
            r1.v = Xr[(size_t)node * RW8 + 16 + t];
#pragma unroll
            for (int p = 0; p < 4; p++) {
                if constexpr (BN) {
                    a0.h[p] = sw2 * pkmax0(sc[p] * r0.h[p] + sh[p]);
                    a1.h[p] = sw2 * pkmax0(sc[4 + p] * r1.h[p] + sh[4 + p]);
                } else {
                    a0.h[p] = sw2 * r0.h[p];
                    a1.h[p] = sw2 * r1.h[p];
                }
            }
        }
        auto edge = [&](int j) {
            const int   idx = __shfl(pidx, sb + j);
            const float wv  = __shfl(pw,  sb + j);
            if (j < deg) {
                const f16x2 w2 = (f16x2)(_Float16)wv;
                U8 r0, r1;
                r0.v = Xr[(size_t)idx * RW8 + t];
                r1.v = Xr[(size_t)idx * RW8 + 16 + t];
#pragma unroll
                for (int p = 0; p < 4; p++) {
                    if constexpr (BN) {
                        a0.h[p] = w2 * pkmax0(sc[p] * r0.h[p] + sh[p]) + a0.h[p];
                        a1.h[p] = w2 * pkmax0(sc[4 + p] * r1.h[p] + sh[4 + p]) + a1.h[p];
                    } else {
                        a0.h[p] = w2 * r0.h[p] + a0.h[p];
                        a1.h[p] = w2 * r1.h[p] + a1.h[p];
                    }
                }
            }
        };
#pragma unroll
        for (int j = 0; j < 8; j++) edge(j);
        if (__any(deg > 8)) {
#pragma unroll
            for (int j = 8; j < 16; j++) edge(j);
            if (__any(deg > 16)) {
                for (int j = 16; j < deg; j++) {
                    const int2 ed = edat[e0 + j];
                    const f16x2 w2 = (f16x2)(_Float16)__int_as_float(ed.y);
                    U8 r0, r1;
                    r0.v = Xr[(size_t)ed.x * RW8 + t];
                    r1.v = Xr[(size_t)ed.x * RW8 + 16 + t];
#pragma unroll
                    for (int p = 0; p < 4; p++) {
                        if constexpr (BN) {
                            a0.h[p] = w2 * pkmax0(sc[p] * r0.h[p] + sh[p]) + a0.h[p];
                            a1.h[p] = w2 * pkmax0(sc[4 + p] * r1.h[p] + sh[4 + p]) + a1.h[p];
                        } else {
                            a0.h[p] = w2 * r0.h[p] + a0.h[p];
                            a1.h[p] = w2 * r1.h[p] + a1.h[p];
                        }
                    }
                }
            }
        }
        *(f16x8*)&At[(wave * 4 + sub) * LROW + t * 8] = a0.v;
        *(f16x8*)&At[(wave * 4 + sub) * LROW + 128 + t * 8] = a1.v;
    }
    __syncthreads();

    // ---- phase 2: MFMA f16 ----
    const int rowb = blockIdx.x * 16;
    const int ntile0 = wave * 4;
    const _Float16* aL = &At[(lane & 15) * LROW + (lane >> 4) * 8];
    f32x4 acc[4] = {};
#pragma unroll
    for (int kt = 0; kt < nkt; kt++) {
        f16x8 af = *(const f16x8*)(aL + kt * 32);
#pragma unroll
        for (int nt = 0; nt < 4; nt++) {
            f16x8 bfr = *(const f16x8*)(Bp + (((size_t)(ntile0 + nt) * nkt + kt) * 64 + lane) * 8);
            acc[nt] = __builtin_amdgcn_mfma_f32_16x16x32_f16(af, bfr, acc[nt], 0, 0, 0);
        }
    }
    const int rg = lane >> 4, cc = lane & 15;    // C/D: col=lane&15, row=rg*4+i
    float s[4], q2[4];
#pragma unroll
    for (int nt = 0; nt < 4; nt++) {
        const int col = (ntile0 + nt) * 16 + cc;
        const float b = bias[col];
        f32x4 a = acc[nt];
        a[0] += b; a[1] += b; a[2] += b; a[3] += b;
        const size_t base = (size_t)(rowb + rg * 4) * HIDDEN + col;
#pragma unroll
        for (int i = 0; i < 4; i++) C[base + (size_t)i * HIDDEN] = (_Float16)a[i];
        s[nt] = a[0] + a[1] + a[2] + a[3];
        q2[nt] = a[0]*a[0] + a[1]*a[1] + a[2]*a[2] + a[3]*a[3];
    }
#pragma unroll
    for (int nt = 0; nt < 4; nt++) {
        s[nt] += __shfl_xor(s[nt], 16); s[nt] += __shfl_xor(s[nt], 32);
        q2[nt] += __shfl_xor(q2[nt], 16); q2[nt] += __shfl_xor(q2[nt], 32);
    }
    if (lane < 16) {
        float* dst = bnp + (size_t)blockIdx.x * 512 + ntile0 * 16 + lane;
#pragma unroll
        for (int nt = 0; nt < 4; nt++) {
            dst[nt * 16]       = s[nt];
            dst[nt * 16 + 256] = q2[nt];
        }
    }
}

// ---------------- BN partial reduce: bnp[GNB][512] -> bnp2[32][512] ----------
__global__ __launch_bounds__(512) void k_bnred(const float* __restrict__ bnp,
                                               float* __restrict__ bnp2) {
    const int t = threadIdx.x;
    const int b = blockIdx.x;                  // 32
    const int per = (GNB + 31) / 32;           // 98
    int r0 = b * per, r1 = r0 + per; if (r1 > GNB) r1 = GNB;
    float s = 0.f;
    for (int r = r0; r < r1; r++) s += bnp[(size_t)r * 512 + t];
    bnp2[(size_t)b * 512 + t] = s;
}

// ---------------- BN prep: bnp2 -> scale/shift ----------------
__global__ __launch_bounds__(256) void k_bnprep(const float* __restrict__ bnp2,
                                                const float* __restrict__ g,
                                                const float* __restrict__ be,
                                                float* __restrict__ scale,
                                                float* __restrict__ shift) {
    const int f = threadIdx.x;
    float s = 0.f, q = 0.f;
#pragma unroll
    for (int b = 0; b < 32; b++) {
        s += bnp2[(size_t)b * 512 + f];
        q += bnp2[(size_t)b * 512 + 256 + f];
    }
    const float inv_n = 1.0f / (float)N_NODES;
    float mean = s * inv_n;
    float var = q * inv_n - mean * mean;
    var = fmaxf(var, 0.f);
    float sc = g[f] * rsqrtf(var + BN_EPS);
    scale[f] = sc;
    shift[f] = be[f] - mean * sc;
}

// ---------------- GEMM3: XW3 = relu(bn(H2)) @ W3, fp32 out, 1 wave MT=3 ------
template <int K_>
__global__ __launch_bounds__(64) void k_gemm3(const _Float16* __restrict__ A,
                                              const _Float16* __restrict__ Bp,
                                              const float* __restrict__ scale,
                                              const float* __restrict__ shift,
                                              float* __restrict__ C) {
    constexpr int nkt = K_ / 32;
    constexpr int MT = 3;
    const int lane = threadIdx.x & 63;
    const int rowb = blockIdx.x * 16;
    const int koff = (lane >> 4) * 8;
    const _Float16* aptr = A + (size_t)(rowb + (lane & 15)) * K_ + koff;
    f32x4 acc[MT] = {};
#pragma unroll
    for (int kt = 0; kt < nkt; kt++) {
        union { f16x8 v; f16x2 h[4]; } au, tu;
        au.v = *(const f16x8*)(aptr + kt * 32);
        const int kb = kt * 32 + koff;
#pragma unroll
        for (int p = 0; p < 4; p++) {
            f16x2 sc2 = {(_Float16)scale[kb + 2 * p], (_Float16)scale[kb + 2 * p + 1]};
            f16x2 sh2 = {(_Float16)shift[kb + 2 * p], (_Float16)shift[kb + 2 * p + 1]};
            tu.h[p] = pkmax0(sc2 * au.h[p] + sh2);
        }
#pragma unroll
        for (int nt = 0; nt < MT; nt++) {
            f16x8 bfr = *(const f16x8*)(Bp + (((size_t)nt * nkt + kt) * 64 + lane) * 8);
            acc[nt] = __builtin_amdgcn_mfma_f32_16x16x32_f16(tu.v, bfr, acc[nt], 0, 0, 0);
        }
    }
    const int rg = lane >> 4, cc = lane & 15;
#pragma unroll
    for (int nt = 0; nt < MT; nt++) {
        const int col = nt * 16 + cc;
        if (col < NCLS) {
            const size_t base = (size_t)(rowb + rg * 4) * NCLS + col;
#pragma unroll
            for (int i = 0; i < 4; i++) C[base + (size_t)i * NCLS] = acc[nt][i];
        }
    }
}

// ---------------- output: gather F=40 + bias + log_softmax, one wave/node ----
// edge (src,w) preloaded into the wave's lanes, shfl-broadcast per edge.
__global__ __launch_bounds__(256) void k_out(const float* __restrict__ XW,
                                             const int* __restrict__ rowp,
                                             const int2* __restrict__ edat,
                                             const float* __restrict__ dinv,
                                             const float* __restrict__ bias,
                                             float* __restrict__ out) {
    const int wave = threadIdx.x >> 6;
    const int lane = threadIdx.x & 63;
    const int node = blockIdx.x * 4 + wave;
    const float dd = dinv[node];
    const bool act = lane < NCLS;
    const int e0 = rowp[node], e1 = rowp[node + 1];
    const int deg = e1 - e0;
    int pidx = 0; float pw = 0.f;
    if (lane < deg) {
        const int2 e = edat[e0 + lane];
        pidx = e.x; pw = __int_as_float(e.y);
    }
    float acc = 0.f;
    if (act) acc = dd * dd * XW[(size_t)node * NCLS + lane];
    auto edge = [&](int j) {
        const int idx = __shfl(pidx, j);
        const float w = __shfl(pw, j);
        if (j < deg && act) acc += w * XW[(size_t)idx * NCLS + lane];
    };
#pragma unroll
    for (int j = 0; j < 8; j++) edge(j);
    for (int base = 8; base < 64; base += 8) {
        if (!__any(deg > base)) break;
#pragma unroll 8
        for (int jj = 0; jj < 8; jj++) edge(base + jj);
    }
    if (__any(deg > 64)) {
        for (int j = 64; j < deg; j++) {
            const int2 ed = edat[e0 + j];
            if (act) acc += __int_as_float(ed.y) * XW[(size_t)ed.x * NCLS + lane];
        }
    }
    if (act) acc += bias[lane];
    float m = act ? acc : -1e30f;
#pragma unroll
    for (int off = 32; off > 0; off >>= 1) m = fmaxf(m, __shfl_xor(m, off));
    float e = act ? expf(acc - m) : 0.f;
#pragma unroll
    for (int off = 32; off > 0; off >>= 1) e += __shfl_xor(e, off);
    const float lse = m + logf(e);
    if (act) out[node * NCLS + lane] = acc - lse;
}

extern "C" void kernel_launch(void* const* d_in, const int* in_sizes, int n_in,
                              void* d_out, int out_size, void* d_ws, size_t ws_size,
                              hipStream_t stream) {
    const float* x   = (const float*)d_in[0];
    const int*   ei  = (const int*)d_in[1];
    const float* W1  = (const float*)d_in[2];
    const float* b1  = (const float*)d_in[3];
    const float* g1  = (const float*)d_in[4];
    const float* be1 = (const float*)d_in[5];
    const float* W2  = (const float*)d_in[6];
    const float* b2  = (const float*)d_in[7];
    const float* g2  = (const float*)d_in[8];
    const float* be2 = (const float*)d_in[9];
    const float* W3  = (const float*)d_in[10];
    const float* b3  = (const float*)d_in[11];
    float* out = (float*)d_out;

    const int* e_src = ei;
    const int* e_dst = ei + N_EDGES;

    // ---- workspace layout ----
    char* w = (char*)d_ws;
    _Float16* Xh  = (_Float16*)w;              w += (size_t)N_NODES * IN_FEAT * 2;  // 12.8 MB
    _Float16* H1h = (_Float16*)w;              w += (size_t)N_NODES * HIDDEN * 2;   // 25.6 MB
    _Float16* H2h = (_Float16*)w;              w += (size_t)N_NODES * HIDDEN * 2;   // 25.6 MB
    float* XW3    = (float*)w;                 w += (size_t)N_NODES * NCLS * 4;     // 8 MB
    float* bnp    = (float*)w;                 w += (size_t)GNB * 512 * 4;          // 6.4 MB
    float* bnp2   = (float*)w;                 w += (size_t)32 * 512 * 4;           // 64 KB
    float* dinv   = (float*)w;                 w += (size_t)N_NODES * 4;
    int2*  edat   = (int2*)w;                  w += (size_t)N_EDGES * 8;            // 2.56 MB
    int*   counts = (int*)w;                   w += (size_t)N_NODES * 4;
    int*   rowp   = (int*)w;                   w += (size_t)(N_NODES + 4) * 4;
    int*   cursor = (int*)w;                   w += (size_t)N_NODES * 4;
    int*   partials=(int*)w;                   w += 256 * 4;
    float* scale1 = (float*)w;                 w += 256 * 4;
    float* shift1 = (float*)w;                 w += 256 * 4;
    float* scale2 = (float*)w;                 w += 256 * 4;
    float* shift2 = (float*)w;                 w += 256 * 4;
    _Float16* W1p = (_Float16*)w;              w += (size_t)16 * 4 * 64 * 8 * 2;    // 64 KB
    _Float16* W2p = (_Float16*)w;              w += (size_t)16 * 8 * 64 * 8 * 2;    // 128 KB
    _Float16* W3p = (_Float16*)w;              w += (size_t)3 * 8 * 64 * 8 * 2;     // 24 KB

    const int EB = (N_EDGES + 255) / 256;

    // ---- CSR build + prep (hist fused with cast/pack) ----
    hipMemsetAsync(counts, 0, (size_t)N_NODES * 4, stream);
    k_prep<<<PREP_HIST_NB + PREP_CVT_NB + PREP_PACK_NB, 256, 0, stream>>>(
        e_dst, counts, x, Xh, W1, W2, W3, W1p, W2p, W3p);
    k_scan_local<<<SCAN_NB, SCAN_B, 0, stream>>>(counts, rowp, partials);
    k_scan_add<<<SCAN_NB, SCAN_B, 0, stream>>>(rowp, cursor, partials, counts, dinv);
    k_scatter<<<EB, 256, 0, stream>>>(e_src, e_dst, cursor, dinv, edat);

    // ---- layer 1: fused (gather X -> MFMA W1 + b1 -> H1h, stats) ----
    k_fused<IN_FEAT, false><<<GNB, 256, 0, stream>>>(
        Xh, rowp, edat, dinv, nullptr, nullptr, W1p, b1, H1h, bnp);
    k_bnred<<<32, 512, 0, stream>>>(bnp, bnp2);
    k_bnprep<<<1, 256, 0, stream>>>(bnp2, g1, be1, scale1, shift1);

    // ---- layer 2: fused (gather relu(bn(H1)) -> MFMA W2 + b2 -> H2h, stats) --
    k_fused<HIDDEN, true><<<GNB, 256, 0, stream>>>(
        H1h, rowp, edat, dinv, scale1, shift1, W2p, b2, H2h, bnp);
    k_bnred<<<32, 512, 0, stream>>>(bnp, bnp2);
    k_bnprep<<<1, 256, 0, stream>>>(bnp2, g2, be2, scale2, shift2);

    // ---- output layer ----
    k_gemm3<HIDDEN><<<GNB, 64, 0, stream>>>(H2h, W3p, scale2, shift2, XW3);
    k_out<<<N_NODES / 4, 256, 0, stream>>>(XW3, rowp, edat, dinv, b3, out);
}

// Round 2
// 260.710 us; speedup vs baseline: 1.2017x; 1.1457x over previous
//
#include <hip/hip_runtime.h>

#define N_NODES 50000
#define N_EDGES 320000
#define IN_FEAT 128
#define HIDDEN  256
#define NCLS    40
#define BN_EPS  1e-5f

#define SCAN_B  256
#define SCAN_NB ((N_NODES + SCAN_B - 1) / SCAN_B)   // 196
#define GNB     (N_NODES / 16)                      // 3125 blocks, 16 nodes each

// prep kernel partition
#define PREP_HIST_NB  (N_EDGES / 256)               // 1250
#define PREP_CVT_NB   (N_NODES * IN_FEAT / 8 / 256) // 3125
#define PREP_PACK_NB  54                            // 216 wave-units / 4
#define BNA_NB        (N_NODES * HIDDEN / 8 / 256)  // 6250

typedef __attribute__((ext_vector_type(8))) _Float16 f16x8;
typedef __attribute__((ext_vector_type(2))) _Float16 f16x2;
typedef __attribute__((ext_vector_type(4))) float f32x4;

__device__ __forceinline__ f16x2 pkmax0(f16x2 a) {
    return __builtin_elementwise_max(a, (f16x2)(_Float16)0.f);
}

__device__ __forceinline__ void packB_unit(const float* __restrict__ W,
                                           _Float16* __restrict__ Bp,
                                           int nt, int kt, int nkt, int M, int lane) {
    const int n = nt * 16 + (lane & 15);
    const int kb = kt * 32 + (lane >> 4) * 8;
    _Float16* dst = Bp + (((size_t)nt * nkt + kt) * 64 + lane) * 8;
#pragma unroll
    for (int j = 0; j < 8; j++)
        dst[j] = (n < M) ? (_Float16)W[(size_t)(kb + j) * M + n] : (_Float16)0.f;
}

// ---------------- merged prep: hist + x cast + W packs ----------------
__global__ __launch_bounds__(256) void k_prep(const int* __restrict__ e_dst,
                                              int* __restrict__ counts,
                                              const float* __restrict__ x,
                                              _Float16* __restrict__ Xh,
                                              const float* __restrict__ W1,
                                              const float* __restrict__ W2,
                                              const float* __restrict__ W3,
                                              _Float16* __restrict__ W1p,
                                              _Float16* __restrict__ W2p,
                                              _Float16* __restrict__ W3p) {
    const int b = blockIdx.x;
    const int tid = threadIdx.x;
    if (b < PREP_HIST_NB) {
        const int e = b * 256 + tid;                  // 1250*256 == N_EDGES
        atomicAdd(&counts[e_dst[e]], 1);
    } else if (b < PREP_HIST_NB + PREP_CVT_NB) {
        const int i = (b - PREP_HIST_NB) * 256 + tid; // exact cover
        float4 a = *(const float4*)(x + (size_t)i * 8);
        float4 c = *(const float4*)(x + (size_t)i * 8 + 4);
        f16x8 o = {(_Float16)a.x, (_Float16)a.y, (_Float16)a.z, (_Float16)a.w,
                   (_Float16)c.x, (_Float16)c.y, (_Float16)c.z, (_Float16)c.w};
        *(f16x8*)&Xh[(size_t)i * 8] = o;
    } else {
        const int wave = tid >> 6, lane = tid & 63;
        const int u = (b - PREP_HIST_NB - PREP_CVT_NB) * 4 + wave;  // 0..215
        if (u < 64) {
            packB_unit(W1, W1p, u >> 2, u & 3, 4, HIDDEN, lane);
        } else if (u < 192) {
            const int v = u - 64;
            packB_unit(W2, W2p, v >> 3, v & 7, 8, HIDDEN, lane);
        } else {
            const int v = u - 192;
            packB_unit(W3, W3p, v >> 3, v & 7, 8, NCLS, lane);
        }
    }
}

// ---------------- CSR scan ----------------
__global__ __launch_bounds__(SCAN_B) void k_scan_local(const int* __restrict__ counts,
                                                       int* __restrict__ rowp,
                                                       int* __restrict__ partials) {
    __shared__ int s[SCAN_B];
    const int tid = threadIdx.x;
    const int i = blockIdx.x * SCAN_B + tid;
    int v = (i < N_NODES) ? counts[i] : 0;
    s[tid] = v;
    __syncthreads();
    for (int off = 1; off < SCAN_B; off <<= 1) {
        int t = (tid >= off) ? s[tid - off] : 0;
        __syncthreads();
        s[tid] += t;
        __syncthreads();
    }
    if (i < N_NODES) rowp[i] = s[tid] - v;
    if (tid == SCAN_B - 1) partials[blockIdx.x] = s[SCAN_B - 1];
}

__global__ __launch_bounds__(SCAN_B) void k_scan_add(int* __restrict__ rowp,
                                                     int* __restrict__ cursor,
                                                     const int* __restrict__ partials,
                                                     const int* __restrict__ counts,
                                                     float* __restrict__ dinv) {
    __shared__ int s[SCAN_B];
    const int tid = threadIdx.x;
    const int b = blockIdx.x;
    int v = (tid < b) ? partials[tid] : 0;
    s[tid] = v;
    __syncthreads();
    for (int off = SCAN_B / 2; off > 0; off >>= 1) {
        if (tid < off) s[tid] += s[tid + off];
        __syncthreads();
    }
    const int offset = s[0];
    const int i = b * SCAN_B + tid;
    if (i < N_NODES) {
        int r = rowp[i] + offset;
        rowp[i] = r;
        cursor[i] = r;
        dinv[i] = rsqrtf(1.0f + (float)counts[i]);
    }
    if (b == 0 && tid == 0) rowp[N_NODES] = N_EDGES;
}

// scatter: packed (src, wnorm) per edge -> single 8B random store
__global__ void k_scatter(const int* __restrict__ src, const int* __restrict__ dst,
                          int* __restrict__ cursor, const float* __restrict__ dinv,
                          int2* __restrict__ edat) {
    int e = blockIdx.x * blockDim.x + threadIdx.x;
    if (e < N_EDGES) {
        int d = dst[e], s = src[e];
        int p = atomicAdd(&cursor[d], 1);
        int2 v; v.x = s; v.y = __float_as_int(dinv[s] * dinv[d]);
        edat[p] = v;
    }
}

// ---------------- fused layer: parallel-row gather -> LDS -> MFMA f16 --------
// Block: 16 nodes, 4 per wave via 16-lane subgroups. Edge loop is 16 flat
// predicated slots (no ballot/branch; exec-masked slots issue no traffic).
// BN/ReLU is NOT here — hoisted to k_bnapply (per-node, not per-edge).
// Stats accumulate straight into 32-bucket bnp2 via atomics (no bnred pass).
template <int KIN>
__global__ __launch_bounds__(256, 4) void k_fused(const _Float16* __restrict__ Xin,
                                                  const int* __restrict__ rowp,
                                                  const int2* __restrict__ edat,
                                                  const float* __restrict__ dinv,
                                                  const _Float16* __restrict__ Bp,
                                                  const float* __restrict__ bias,
                                                  _Float16* __restrict__ C,
                                                  float* __restrict__ bnp2) {
    constexpr int nkt = KIN / 32;
    constexpr int LROW = KIN + 8;
    constexpr int RW8 = KIN / 8;                 // f16x8 words per feature row
    constexpr int NL = KIN / 128;                // f16x8 loads per lane per row
    __shared__ __align__(16) _Float16 At[16 * LROW];
    const int wave = threadIdx.x >> 6;
    const int lane = threadIdx.x & 63;
    const int sub  = lane >> 4;                  // node slot within wave
    const int t    = lane & 15;                  // lane within subgroup
    const int sb   = lane & 48;                  // subgroup base lane
    const int node = blockIdx.x * 16 + wave * 4 + sub;

    const int e0 = rowp[node];
    const int e1 = rowp[node + 1];
    const int deg = e1 - e0;
    // coalesced preload of up to 16 (src, w) pairs into the subgroup's lanes
    int   pidx = 0;
    float pw   = 0.f;
    if (t < deg) {
        const int2 e = edat[e0 + t];
        pidx = e.x;
        pw = __int_as_float(e.y);
    }
    const float dd = dinv[node];
    const f16x2 sw2 = (f16x2)(_Float16)(dd * dd);

    const f16x8* __restrict__ Xr = (const f16x8*)Xin;
    union U8 { f16x8 v; f16x2 h[4]; };

    U8 a[NL];
    {
        U8 r[NL];
#pragma unroll
        for (int q = 0; q < NL; q++) r[q].v = Xr[(size_t)node * RW8 + q * 16 + t];
#pragma unroll
        for (int q = 0; q < NL; q++)
#pragma unroll
            for (int p = 0; p < 4; p++) a[q].h[p] = sw2 * r[q].h[p];
    }
    auto edge = [&](int j) {
        const int   idx = __shfl(pidx, sb + j);
        const float wv  = __shfl(pw,  sb + j);
        if (j < deg) {
            const f16x2 w2 = (f16x2)(_Float16)wv;
            U8 r[NL];
#pragma unroll
            for (int q = 0; q < NL; q++) r[q].v = Xr[(size_t)idx * RW8 + q * 16 + t];
#pragma unroll
            for (int q = 0; q < NL; q++)
#pragma unroll
                for (int p = 0; p < 4; p++) a[q].h[p] = w2 * r[q].h[p] + a[q].h[p];
        }
    };
#pragma unroll
    for (int j = 0; j < 16; j++) edge(j);
    if (__any(deg > 16)) {
        for (int j = 16; j < deg; j++) {
            const int2 ed = edat[e0 + j];
            const f16x2 w2 = (f16x2)(_Float16)__int_as_float(ed.y);
            U8 r[NL];
#pragma unroll
            for (int q = 0; q < NL; q++) r[q].v = Xr[(size_t)ed.x * RW8 + q * 16 + t];
#pragma unroll
            for (int q = 0; q < NL; q++)
#pragma unroll
                for (int p = 0; p < 4; p++) a[q].h[p] = w2 * r[q].h[p] + a[q].h[p];
        }
    }
#pragma unroll
    for (int q = 0; q < NL; q++)
        *(f16x8*)&At[(wave * 4 + sub) * LROW + q * 128 + t * 8] = a[q].v;
    __syncthreads();

    // ---- phase 2: MFMA f16 ----
    const int rowb = blockIdx.x * 16;
    const int ntile0 = wave * 4;
    const _Float16* aL = &At[(lane & 15) * LROW + (lane >> 4) * 8];
    f32x4 acc[4] = {};
#pragma unroll
    for (int kt = 0; kt < nkt; kt++) {
        f16x8 af = *(const f16x8*)(aL + kt * 32);
#pragma unroll
        for (int nt = 0; nt < 4; nt++) {
            f16x8 bfr = *(const f16x8*)(Bp + (((size_t)(ntile0 + nt) * nkt + kt) * 64 + lane) * 8);
            acc[nt] = __builtin_amdgcn_mfma_f32_16x16x32_f16(af, bfr, acc[nt], 0, 0, 0);
        }
    }
    const int rg = lane >> 4, cc = lane & 15;    // C/D: col=lane&15, row=rg*4+i
    float s[4], q2[4];
#pragma unroll
    for (int nt = 0; nt < 4; nt++) {
        const int col = (ntile0 + nt) * 16 + cc;
        const float b = bias[col];
        f32x4 a2 = acc[nt];
        a2[0] += b; a2[1] += b; a2[2] += b; a2[3] += b;
        const size_t base = (size_t)(rowb + rg * 4) * HIDDEN + col;
#pragma unroll
        for (int i = 0; i < 4; i++) C[base + (size_t)i * HIDDEN] = (_Float16)a2[i];
        s[nt] = a2[0] + a2[1] + a2[2] + a2[3];
        q2[nt] = a2[0]*a2[0] + a2[1]*a2[1] + a2[2]*a2[2] + a2[3]*a2[3];
    }
#pragma unroll
    for (int nt = 0; nt < 4; nt++) {
        s[nt] += __shfl_xor(s[nt], 16); s[nt] += __shfl_xor(s[nt], 32);
        q2[nt] += __shfl_xor(q2[nt], 16); q2[nt] += __shfl_xor(q2[nt], 32);
    }
    if (lane < 16) {
        float* dst = bnp2 + ((blockIdx.x & 31) * 512) + ntile0 * 16 + lane;
#pragma unroll
        for (int nt = 0; nt < 4; nt++) {
            atomicAdd(&dst[nt * 16], s[nt]);
            atomicAdd(&dst[nt * 16 + 256], q2[nt]);
        }
    }
}

// ---------------- BN prep: bnp2[32][512] -> scale/shift ----------------
__global__ __launch_bounds__(256) void k_bnprep(const float* __restrict__ bnp2,
                                                const float* __restrict__ g,
                                                const float* __restrict__ be,
                                                float* __restrict__ scale,
                                                float* __restrict__ shift) {
    const int f = threadIdx.x;
    float s = 0.f, q = 0.f;
#pragma unroll
    for (int b = 0; b < 32; b++) {
        s += bnp2[(size_t)b * 512 + f];
        q += bnp2[(size_t)b * 512 + 256 + f];
    }
    const float inv_n = 1.0f / (float)N_NODES;
    float mean = s * inv_n;
    float var = q * inv_n - mean * mean;
    var = fmaxf(var, 0.f);
    float sc = g[f] * rsqrtf(var + BN_EPS);
    scale[f] = sc;
    shift[f] = be[f] - mean * sc;
}

// ---------------- BN apply (in-place): H = relu(bn(H)) ----------------
__global__ __launch_bounds__(256) void k_bnapply(_Float16* __restrict__ H,
                                                 const float* __restrict__ scale,
                                                 const float* __restrict__ shift) {
    const size_t i = (size_t)blockIdx.x * 256 + threadIdx.x;  // f16x8 index
    const int f0 = (int)(i & 31) * 8;                         // feat offset
    union U8 { f16x8 v; f16x2 h[4]; } r;
    r.v = ((const f16x8*)H)[i];
#pragma unroll
    for (int p = 0; p < 4; p++) {
        f16x2 sc = {(_Float16)scale[f0 + 2 * p], (_Float16)scale[f0 + 2 * p + 1]};
        f16x2 sh = {(_Float16)shift[f0 + 2 * p], (_Float16)shift[f0 + 2 * p + 1]};
        r.h[p] = pkmax0(sc * r.h[p] + sh);
    }
    ((f16x8*)H)[i] = r.v;
}

// ---------------- GEMM3: XW3 = relu(bn(H2)) @ W3, fp16 out, 1 wave MT=3 ------
template <int K_>
__global__ __launch_bounds__(64) void k_gemm3(const _Float16* __restrict__ A,
                                              const _Float16* __restrict__ Bp,
                                              const float* __restrict__ scale,
                                              const float* __restrict__ shift,
                                              _Float16* __restrict__ C) {
    constexpr int nkt = K_ / 32;
    constexpr int MT = 3;
    const int lane = threadIdx.x & 63;
    const int rowb = blockIdx.x * 16;
    const int koff = (lane >> 4) * 8;
    const _Float16* aptr = A + (size_t)(rowb + (lane & 15)) * K_ + koff;
    f32x4 acc[MT] = {};
#pragma unroll
    for (int kt = 0; kt < nkt; kt++) {
        union { f16x8 v; f16x2 h[4]; } au, tu;
        au.v = *(const f16x8*)(aptr + kt * 32);
        const int kb = kt * 32 + koff;
#pragma unroll
        for (int p = 0; p < 4; p++) {
            f16x2 sc2 = {(_Float16)scale[kb + 2 * p], (_Float16)scale[kb + 2 * p + 1]};
            f16x2 sh2 = {(_Float16)shift[kb + 2 * p], (_Float16)shift[kb + 2 * p + 1]};
            tu.h[p] = pkmax0(sc2 * au.h[p] + sh2);
        }
#pragma unroll
        for (int nt = 0; nt < MT; nt++) {
            f16x8 bfr = *(const f16x8*)(Bp + (((size_t)nt * nkt + kt) * 64 + lane) * 8);
            acc[nt] = __builtin_amdgcn_mfma_f32_16x16x32_f16(tu.v, bfr, acc[nt], 0, 0, 0);
        }
    }
    const int rg = lane >> 4, cc = lane & 15;
#pragma unroll
    for (int nt = 0; nt < MT; nt++) {
        const int col = nt * 16 + cc;
        if (col < NCLS) {
            const size_t base = (size_t)(rowb + rg * 4) * NCLS + col;
#pragma unroll
            for (int i = 0; i < 4; i++) C[base + (size_t)i * NCLS] = (_Float16)acc[nt][i];
        }
    }
}

// ---------------- output: gather F=40 (fp16) + bias + log_softmax ----------
__global__ __launch_bounds__(256) void k_out(const _Float16* __restrict__ XW,
                                             const int* __restrict__ rowp,
                                             const int2* __restrict__ edat,
                                             const float* __restrict__ dinv,
                                             const float* __restrict__ bias,
                                             float* __restrict__ out) {
    const int wave = threadIdx.x >> 6;
    const int lane = threadIdx.x & 63;
    const int node = blockIdx.x * 4 + wave;
    const float dd = dinv[node];
    const bool act = lane < NCLS;
    const int e0 = rowp[node], e1 = rowp[node + 1];
    const int deg = e1 - e0;
    int pidx = 0; float pw = 0.f;
    if (lane < deg) {
        const int2 e = edat[e0 + lane];
        pidx = e.x; pw = __int_as_float(e.y);
    }
    const _Float16* Xl = XW + lane;
    float acc = 0.f;
    if (act) acc = dd * dd * (float)Xl[(size_t)node * NCLS];
    auto edge = [&](int j) {
        const int idx = __shfl(pidx, j);
        const float w = __shfl(pw, j);
        if (j < deg && act) acc += w * (float)Xl[(size_t)idx * NCLS];
    };
#pragma unroll
    for (int j = 0; j < 16; j++) edge(j);
    if (__any(deg > 16)) {
#pragma unroll 16
        for (int j = 16; j < 32; j++) edge(j);
        if (__any(deg > 32)) {
#pragma unroll 16
            for (int j = 32; j < 48; j++) edge(j);
            if (__any(deg > 48)) {
#pragma unroll 16
                for (int j = 48; j < 64; j++) edge(j);
                if (__any(deg > 64)) {
                    for (int j = 64; j < deg; j++) {
                        const int2 ed = edat[e0 + j];
                        if (act) acc += __int_as_float(ed.y) * (float)Xl[(size_t)ed.x * NCLS];
                    }
                }
            }
        }
    }
    if (act) acc += bias[lane];
    float m = act ? acc : -1e30f;
#pragma unroll
    for (int off = 32; off > 0; off >>= 1) m = fmaxf(m, __shfl_xor(m, off));
    float e = act ? expf(acc - m) : 0.f;
#pragma unroll
    for (int off = 32; off > 0; off >>= 1) e += __shfl_xor(e, off);
    const float lse = m + logf(e);
    if (act) out[node * NCLS + lane] = acc - lse;
}

extern "C" void kernel_launch(void* const* d_in, const int* in_sizes, int n_in,
                              void* d_out, int out_size, void* d_ws, size_t ws_size,
                              hipStream_t stream) {
    const float* x   = (const float*)d_in[0];
    const int*   ei  = (const int*)d_in[1];
    const float* W1  = (const float*)d_in[2];
    const float* b1  = (const float*)d_in[3];
    const float* g1  = (const float*)d_in[4];
    const float* be1 = (const float*)d_in[5];
    const float* W2  = (const float*)d_in[6];
    const float* b2  = (const float*)d_in[7];
    const float* g2  = (const float*)d_in[8];
    const float* be2 = (const float*)d_in[9];
    const float* W3  = (const float*)d_in[10];
    const float* b3  = (const float*)d_in[11];
    float* out = (float*)d_out;

    const int* e_src = ei;
    const int* e_dst = ei + N_EDGES;

    // ---- workspace layout ----
    char* w = (char*)d_ws;
    _Float16* Xh  = (_Float16*)w;              w += (size_t)N_NODES * IN_FEAT * 2;  // 12.8 MB
    _Float16* H1h = (_Float16*)w;              w += (size_t)N_NODES * HIDDEN * 2;   // 25.6 MB
    _Float16* H2h = (_Float16*)w;              w += (size_t)N_NODES * HIDDEN * 2;   // 25.6 MB
    _Float16* XW3h = (_Float16*)w;             w += (size_t)N_NODES * NCLS * 2;     // 4 MB
    float* dinv   = (float*)w;                 w += (size_t)N_NODES * 4;
    int2*  edat   = (int2*)w;                  w += (size_t)N_EDGES * 8;            // 2.56 MB
    // --- contiguous zero-init region (single memset) ---
    int*   counts = (int*)w;                   w += (size_t)N_NODES * 4;            // 200000 B
    float* bnp2a  = (float*)w;                 w += (size_t)32 * 512 * 4;           // 64 KB
    float* bnp2b  = (float*)w;                 w += (size_t)32 * 512 * 4;           // 64 KB
    // ---
    int*   rowp   = (int*)w;                   w += (size_t)(N_NODES + 4) * 4;
    int*   cursor = (int*)w;                   w += (size_t)N_NODES * 4;
    int*   partials=(int*)w;                   w += 256 * 4;
    float* scale1 = (float*)w;                 w += 256 * 4;
    float* shift1 = (float*)w;                 w += 256 * 4;
    float* scale2 = (float*)w;                 w += 256 * 4;
    float* shift2 = (float*)w;                 w += 256 * 4;
    _Float16* W1p = (_Float16*)w;              w += (size_t)16 * 4 * 64 * 8 * 2;    // 64 KB
    _Float16* W2p = (_Float16*)w;              w += (size_t)16 * 8 * 64 * 8 * 2;    // 128 KB
    _Float16* W3p = (_Float16*)w;              w += (size_t)3 * 8 * 64 * 8 * 2;     // 24 KB

    const int EB = (N_EDGES + 255) / 256;

    // ---- CSR build + prep (hist fused with cast/pack) ----
    hipMemsetAsync(counts, 0, (size_t)N_NODES * 4 + 2 * (size_t)32 * 512 * 4, stream);
    k_prep<<<PREP_HIST_NB + PREP_CVT_NB + PREP_PACK_NB, 256, 0, stream>>>(
        e_dst, counts, x, Xh, W1, W2, W3, W1p, W2p, W3p);
    k_scan_local<<<SCAN_NB, SCAN_B, 0, stream>>>(counts, rowp, partials);
    k_scan_add<<<SCAN_NB, SCAN_B, 0, stream>>>(rowp, cursor, partials, counts, dinv);
    k_scatter<<<EB, 256, 0, stream>>>(e_src, e_dst, cursor, dinv, edat);

    // ---- layer 1: fused (gather X -> MFMA W1 + b1 -> H1h, stats) ----
    k_fused<IN_FEAT><<<GNB, 256, 0, stream>>>(
        Xh, rowp, edat, dinv, W1p, b1, H1h, bnp2a);
    k_bnprep<<<1, 256, 0, stream>>>(bnp2a, g1, be1, scale1, shift1);
    k_bnapply<<<BNA_NB, 256, 0, stream>>>(H1h, scale1, shift1);

    // ---- layer 2: fused (gather H1' -> MFMA W2 + b2 -> H2h, stats) ----
    k_fused<HIDDEN><<<GNB, 256, 0, stream>>>(
        H1h, rowp, edat, dinv, W2p, b2, H2h, bnp2b);
    k_bnprep<<<1, 256, 0, stream>>>(bnp2b, g2, be2, scale2, shift2);

    // ---- output layer ----
    k_gemm3<HIDDEN><<<GNB, 64, 0, stream>>>(H2h, W3p, scale2, shift2, XW3h);
    k_out<<<N_NODES / 4, 256, 0, stream>>>(XW3h, rowp, edat, dinv, b3, out);
}

// Round 3
// 243.059 us; speedup vs baseline: 1.2889x; 1.0726x over previous
//
#include <hip/hip_runtime.h>

#define N_NODES 50000
#define N_EDGES 320000
#define IN_FEAT 128
#define HIDDEN  256
#define NCLS    40
#define BN_EPS  1e-5f

#define SCAN_B  256
#define SCAN_NB ((N_NODES + SCAN_B - 1) / SCAN_B)   // 196
#define GNB     (N_NODES / 16)                      // 3125 blocks, 16 nodes each

// prep kernel partition
#define PREP_HIST_NB  (N_EDGES / 256)               // 1250
#define PREP_CVT_NB   (N_NODES * IN_FEAT / 8 / 256) // 3125
#define PREP_PACK_NB  54                            // 216 wave-units / 4
#define BNA_NB        (N_NODES * HIDDEN / 8 / 256)  // 6250

typedef __attribute__((ext_vector_type(8))) _Float16 f16x8;
typedef __attribute__((ext_vector_type(2))) _Float16 f16x2;
typedef __attribute__((ext_vector_type(4))) float f32x4;

__device__ __forceinline__ f16x2 pkmax0(f16x2 a) {
    return __builtin_elementwise_max(a, (f16x2)(_Float16)0.f);
}

__device__ __forceinline__ void packB_unit(const float* __restrict__ W,
                                           _Float16* __restrict__ Bp,
                                           int nt, int kt, int nkt, int M, int lane) {
    const int n = nt * 16 + (lane & 15);
    const int kb = kt * 32 + (lane >> 4) * 8;
    _Float16* dst = Bp + (((size_t)nt * nkt + kt) * 64 + lane) * 8;
#pragma unroll
    for (int j = 0; j < 8; j++)
        dst[j] = (n < M) ? (_Float16)W[(size_t)(kb + j) * M + n] : (_Float16)0.f;
}

// ---------------- merged prep: hist + x cast + W packs ----------------
__global__ __launch_bounds__(256) void k_prep(const int* __restrict__ e_dst,
                                              int* __restrict__ counts,
                                              const float* __restrict__ x,
                                              _Float16* __restrict__ Xh,
                                              const float* __restrict__ W1,
                                              const float* __restrict__ W2,
                                              const float* __restrict__ W3,
                                              _Float16* __restrict__ W1p,
                                              _Float16* __restrict__ W2p,
                                              _Float16* __restrict__ W3p) {
    const int b = blockIdx.x;
    const int tid = threadIdx.x;
    if (b < PREP_HIST_NB) {
        const int e = b * 256 + tid;                  // 1250*256 == N_EDGES
        atomicAdd(&counts[e_dst[e]], 1);
    } else if (b < PREP_HIST_NB + PREP_CVT_NB) {
        const int i = (b - PREP_HIST_NB) * 256 + tid; // exact cover
        float4 a = *(const float4*)(x + (size_t)i * 8);
        float4 c = *(const float4*)(x + (size_t)i * 8 + 4);
        f16x8 o = {(_Float16)a.x, (_Float16)a.y, (_Float16)a.z, (_Float16)a.w,
                   (_Float16)c.x, (_Float16)c.y, (_Float16)c.z, (_Float16)c.w};
        *(f16x8*)&Xh[(size_t)i * 8] = o;
    } else {
        const int wave = tid >> 6, lane = tid & 63;
        const int u = (b - PREP_HIST_NB - PREP_CVT_NB) * 4 + wave;  // 0..215
        if (u < 64) {
            packB_unit(W1, W1p, u >> 2, u & 3, 4, HIDDEN, lane);
        } else if (u < 192) {
            const int v = u - 64;
            packB_unit(W2, W2p, v >> 3, v & 7, 8, HIDDEN, lane);
        } else {
            const int v = u - 192;
            packB_unit(W3, W3p, v >> 3, v & 7, 8, NCLS, lane);
        }
    }
}

// ---------------- CSR scan ----------------
__global__ __launch_bounds__(SCAN_B) void k_scan_local(const int* __restrict__ counts,
                                                       int* __restrict__ rowp,
                                                       int* __restrict__ partials) {
    __shared__ int s[SCAN_B];
    const int tid = threadIdx.x;
    const int i = blockIdx.x * SCAN_B + tid;
    int v = (i < N_NODES) ? counts[i] : 0;
    s[tid] = v;
    __syncthreads();
    for (int off = 1; off < SCAN_B; off <<= 1) {
        int t = (tid >= off) ? s[tid - off] : 0;
        __syncthreads();
        s[tid] += t;
        __syncthreads();
    }
    if (i < N_NODES) rowp[i] = s[tid] - v;
    if (tid == SCAN_B - 1) partials[blockIdx.x] = s[SCAN_B - 1];
}

__global__ __launch_bounds__(SCAN_B) void k_scan_add(int* __restrict__ rowp,
                                                     int* __restrict__ cursor,
                                                     const int* __restrict__ partials,
                                                     const int* __restrict__ counts,
                                                     float* __restrict__ dinv) {
    __shared__ int s[SCAN_B];
    const int tid = threadIdx.x;
    const int b = blockIdx.x;
    int v = (tid < b) ? partials[tid] : 0;
    s[tid] = v;
    __syncthreads();
    for (int off = SCAN_B / 2; off > 0; off >>= 1) {
        if (tid < off) s[tid] += s[tid + off];
        __syncthreads();
    }
    const int offset = s[0];
    const int i = b * SCAN_B + tid;
    if (i < N_NODES) {
        int r = rowp[i] + offset;
        rowp[i] = r;
        cursor[i] = r;
        dinv[i] = rsqrtf(1.0f + (float)counts[i]);
    }
    if (b == 0 && tid == 0) rowp[N_NODES] = N_EDGES;
}

// scatter: packed (src, wnorm) per edge -> single 8B random store
__global__ void k_scatter(const int* __restrict__ src, const int* __restrict__ dst,
                          int* __restrict__ cursor, const float* __restrict__ dinv,
                          int2* __restrict__ edat) {
    int e = blockIdx.x * blockDim.x + threadIdx.x;
    if (e < N_EDGES) {
        int d = dst[e], s = src[e];
        int p = atomicAdd(&cursor[d], 1);
        int2 v; v.x = s; v.y = __float_as_int(dinv[s] * dinv[d]);
        edat[p] = v;
    }
}

// ---------------- fused layer: parallel-row gather -> LDS -> MFMA f16 --------
// Block: 16 nodes, 4 per wave via 16-lane subgroups. Edge loop is BRANCH-FREE
// batches of 8: dummy slots gather the node's own row (L1 hit) with w=0, so
// all 8*NL loads issue into distinct registers -> deep MLP (the R1 kernel's
// VGPR=32 showed the compiler was recycling one load register per edge).
template <int KIN>
__global__ __launch_bounds__(256, 4) void k_fused(const _Float16* __restrict__ Xin,
                                                  const int* __restrict__ rowp,
                                                  const int2* __restrict__ edat,
                                                  const float* __restrict__ dinv,
                                                  const _Float16* __restrict__ Bp,
                                                  const float* __restrict__ bias,
                                                  _Float16* __restrict__ C,
                                                  float* __restrict__ bnp2) {
    constexpr int nkt = KIN / 32;
    constexpr int LROW = KIN + 8;
    constexpr int RW8 = KIN / 8;                 // f16x8 words per feature row
    constexpr int NL = KIN / 128;                // f16x8 loads per lane per row
    __shared__ __align__(16) _Float16 At[16 * LROW];
    const int wave = threadIdx.x >> 6;
    const int lane = threadIdx.x & 63;
    const int sub  = lane >> 4;                  // node slot within wave
    const int t    = lane & 15;                  // lane within subgroup
    const int sb   = lane & 48;                  // subgroup base lane
    const int node = blockIdx.x * 16 + wave * 4 + sub;

    const int e0 = rowp[node];
    const int deg = rowp[node + 1] - e0;
    // coalesced preload of up to 16 (src, w) pairs into the subgroup's lanes
    int   pidx = 0;
    float pw   = 0.f;
    if (t < deg) {
        const int2 e = edat[e0 + t];
        pidx = e.x;
        pw = __int_as_float(e.y);
    }
    const float dd = dinv[node];
    const f16x2 sw2 = (f16x2)(_Float16)(dd * dd);

    const f16x8* __restrict__ Xr = (const f16x8*)Xin;
    union U8 { f16x8 v; f16x2 h[4]; };

    U8 a[NL];
#pragma unroll
    for (int q = 0; q < NL; q++) {
        U8 r; r.v = Xr[(size_t)node * RW8 + q * 16 + t];
#pragma unroll
        for (int p = 0; p < 4; p++) a[q].h[p] = sw2 * r.h[p];
    }

    auto batch8 = [&](int j0) {
        int bi[8]; _Float16 bw[8];
#pragma unroll
        for (int j = 0; j < 8; j++) {
            const int   v  = __shfl(pidx, sb + j0 + j);
            const float wv = __shfl(pw,  sb + j0 + j);
            const bool ok = (j0 + j) < deg;
            bi[j] = ok ? v : node;                      // dummy: self row (L1 hit)
            bw[j] = ok ? (_Float16)wv : (_Float16)0.f;  // dummy: exact no-op
        }
        U8 r[8][NL];
#pragma unroll
        for (int j = 0; j < 8; j++)
#pragma unroll
            for (int q = 0; q < NL; q++)
                r[j][q].v = Xr[(size_t)bi[j] * RW8 + q * 16 + t];
#pragma unroll
        for (int j = 0; j < 8; j++) {
            const f16x2 w2 = (f16x2)bw[j];
#pragma unroll
            for (int q = 0; q < NL; q++)
#pragma unroll
                for (int p = 0; p < 4; p++) a[q].h[p] = w2 * r[j][q].h[p] + a[q].h[p];
        }
    };
    batch8(0);
    if (__any(deg > 8)) {
        batch8(8);
        if (__any(deg > 16)) {
            for (int j = 16; j < deg; j++) {
                const int2 ed = edat[e0 + j];
                const f16x2 w2 = (f16x2)(_Float16)__int_as_float(ed.y);
#pragma unroll
                for (int q = 0; q < NL; q++) {
                    U8 r; r.v = Xr[(size_t)ed.x * RW8 + q * 16 + t];
#pragma unroll
                    for (int p = 0; p < 4; p++) a[q].h[p] = w2 * r.h[p] + a[q].h[p];
                }
            }
        }
    }
#pragma unroll
    for (int q = 0; q < NL; q++)
        *(f16x8*)&At[(wave * 4 + sub) * LROW + q * 128 + t * 8] = a[q].v;
    __syncthreads();

    // ---- phase 2: MFMA f16 ----
    const int rowb = blockIdx.x * 16;
    const int ntile0 = wave * 4;
    const _Float16* aL = &At[(lane & 15) * LROW + (lane >> 4) * 8];
    f32x4 acc[4] = {};
#pragma unroll
    for (int kt = 0; kt < nkt; kt++) {
        f16x8 af = *(const f16x8*)(aL + kt * 32);
#pragma unroll
        for (int nt = 0; nt < 4; nt++) {
            f16x8 bfr = *(const f16x8*)(Bp + (((size_t)(ntile0 + nt) * nkt + kt) * 64 + lane) * 8);
            acc[nt] = __builtin_amdgcn_mfma_f32_16x16x32_f16(af, bfr, acc[nt], 0, 0, 0);
        }
    }
    const int rg = lane >> 4, cc = lane & 15;    // C/D: col=lane&15, row=rg*4+i
    float s[4], q2[4];
#pragma unroll
    for (int nt = 0; nt < 4; nt++) {
        const int col = (ntile0 + nt) * 16 + cc;
        const float b = bias[col];
        f32x4 a2 = acc[nt];
        a2[0] += b; a2[1] += b; a2[2] += b; a2[3] += b;
        const size_t base = (size_t)(rowb + rg * 4) * HIDDEN + col;
#pragma unroll
        for (int i = 0; i < 4; i++) C[base + (size_t)i * HIDDEN] = (_Float16)a2[i];
        s[nt] = a2[0] + a2[1] + a2[2] + a2[3];
        q2[nt] = a2[0]*a2[0] + a2[1]*a2[1] + a2[2]*a2[2] + a2[3]*a2[3];
    }
#pragma unroll
    for (int nt = 0; nt < 4; nt++) {
        s[nt] += __shfl_xor(s[nt], 16); s[nt] += __shfl_xor(s[nt], 32);
        q2[nt] += __shfl_xor(q2[nt], 16); q2[nt] += __shfl_xor(q2[nt], 32);
    }
    if (lane < 16) {
        float* dst = bnp2 + ((blockIdx.x & 31) * 512) + ntile0 * 16 + lane;
#pragma unroll
        for (int nt = 0; nt < 4; nt++) {
            atomicAdd(&dst[nt * 16], s[nt]);
            atomicAdd(&dst[nt * 16 + 256], q2[nt]);
        }
    }
}

// ---------------- BN prep: bnp2[32][512] -> scale/shift ----------------
__global__ __launch_bounds__(256) void k_bnprep(const float* __restrict__ bnp2,
                                                const float* __restrict__ g,
                                                const float* __restrict__ be,
                                                float* __restrict__ scale,
                                                float* __restrict__ shift) {
    const int f = threadIdx.x;
    float s = 0.f, q = 0.f;
#pragma unroll
    for (int b = 0; b < 32; b++) {
        s += bnp2[(size_t)b * 512 + f];
        q += bnp2[(size_t)b * 512 + 256 + f];
    }
    const float inv_n = 1.0f / (float)N_NODES;
    float mean = s * inv_n;
    float var = q * inv_n - mean * mean;
    var = fmaxf(var, 0.f);
    float sc = g[f] * rsqrtf(var + BN_EPS);
    scale[f] = sc;
    shift[f] = be[f] - mean * sc;
}

// ---------------- BN apply (in-place): H = relu(bn(H)) ----------------
__global__ __launch_bounds__(256) void k_bnapply(_Float16* __restrict__ H,
                                                 const float* __restrict__ scale,
                                                 const float* __restrict__ shift) {
    const size_t i = (size_t)blockIdx.x * 256 + threadIdx.x;  // f16x8 index
    const int f0 = (int)(i & 31) * 8;                         // feat offset
    union U8 { f16x8 v; f16x2 h[4]; } r;
    r.v = ((const f16x8*)H)[i];
#pragma unroll
    for (int p = 0; p < 4; p++) {
        f16x2 sc = {(_Float16)scale[f0 + 2 * p], (_Float16)scale[f0 + 2 * p + 1]};
        f16x2 sh = {(_Float16)shift[f0 + 2 * p], (_Float16)shift[f0 + 2 * p + 1]};
        r.h[p] = pkmax0(sc * r.h[p] + sh);
    }
    ((f16x8*)H)[i] = r.v;
}

// ---------------- GEMM3: XW3 = relu(bn(H2)) @ W3, fp16 out, 1 wave MT=3 ------
template <int K_>
__global__ __launch_bounds__(64) void k_gemm3(const _Float16* __restrict__ A,
                                              const _Float16* __restrict__ Bp,
                                              const float* __restrict__ scale,
                                              const float* __restrict__ shift,
                                              _Float16* __restrict__ C) {
    constexpr int nkt = K_ / 32;
    constexpr int MT = 3;
    const int lane = threadIdx.x & 63;
    const int rowb = blockIdx.x * 16;
    const int koff = (lane >> 4) * 8;
    const _Float16* aptr = A + (size_t)(rowb + (lane & 15)) * K_ + koff;
    f32x4 acc[MT] = {};
#pragma unroll
    for (int kt = 0; kt < nkt; kt++) {
        union { f16x8 v; f16x2 h[4]; } au, tu;
        au.v = *(const f16x8*)(aptr + kt * 32);
        const int kb = kt * 32 + koff;
#pragma unroll
        for (int p = 0; p < 4; p++) {
            f16x2 sc2 = {(_Float16)scale[kb + 2 * p], (_Float16)scale[kb + 2 * p + 1]};
            f16x2 sh2 = {(_Float16)shift[kb + 2 * p], (_Float16)shift[kb + 2 * p + 1]};
            tu.h[p] = pkmax0(sc2 * au.h[p] + sh2);
        }
#pragma unroll
        for (int nt = 0; nt < MT; nt++) {
            f16x8 bfr = *(const f16x8*)(Bp + (((size_t)nt * nkt + kt) * 64 + lane) * 8);
            acc[nt] = __builtin_amdgcn_mfma_f32_16x16x32_f16(tu.v, bfr, acc[nt], 0, 0, 0);
        }
    }
    const int rg = lane >> 4, cc = lane & 15;
#pragma unroll
    for (int nt = 0; nt < MT; nt++) {
        const int col = nt * 16 + cc;
        if (col < NCLS) {
            const size_t base = (size_t)(rowb + rg * 4) * NCLS + col;
#pragma unroll
            for (int i = 0; i < 4; i++) C[base + (size_t)i * NCLS] = (_Float16)acc[nt][i];
        }
    }
}

// ---------------- output: gather F=40 (fp16) + bias + log_softmax ----------
// one wave per node; branch-free batches of 8 edges (dummy idx=node, w=0).
__global__ __launch_bounds__(256) void k_out(const _Float16* __restrict__ XW,
                                             const int* __restrict__ rowp,
                                             const int2* __restrict__ edat,
                                             const float* __restrict__ dinv,
                                             const float* __restrict__ bias,
                                             float* __restrict__ out) {
    const int wave = threadIdx.x >> 6;
    const int lane = threadIdx.x & 63;
    const int node = blockIdx.x * 4 + wave;
    const float dd = dinv[node];
    const bool act = lane < NCLS;
    const int e0 = rowp[node];
    const int deg = rowp[node + 1] - e0;
    int pidx = 0; float pw = 0.f;
    if (lane < deg) {
        const int2 e = edat[e0 + lane];
        pidx = e.x; pw = __int_as_float(e.y);
    }
    const _Float16* Xl = XW + lane;
    float acc = 0.f;
    if (act) acc = dd * dd * (float)Xl[(size_t)node * NCLS];
    auto batch8 = [&](int j0) {
        int bi[8]; float bw[8];
#pragma unroll
        for (int j = 0; j < 8; j++) {
            const int   v  = __shfl(pidx, j0 + j);
            const float wv = __shfl(pw,  j0 + j);
            const bool ok = (j0 + j) < deg;
            bi[j] = ok ? v : node;
            bw[j] = ok ? wv : 0.f;
        }
        if (act) {
            float rv[8];
#pragma unroll
            for (int j = 0; j < 8; j++) rv[j] = (float)Xl[(size_t)bi[j] * NCLS];
#pragma unroll
            for (int j = 0; j < 8; j++) acc += bw[j] * rv[j];
        }
    };
    batch8(0);
    if (deg > 8) {
        batch8(8);
        if (deg > 16) {
            batch8(16);
            if (deg > 24) {
                batch8(24);
                if (deg > 32) {
                    for (int j = 32; j < deg; j++) {
                        const int2 ed = edat[e0 + j];
                        if (act) acc += __int_as_float(ed.y) * (float)Xl[(size_t)ed.x * NCLS];
                    }
                }
            }
        }
    }
    if (act) acc += bias[lane];
    float m = act ? acc : -1e30f;
#pragma unroll
    for (int off = 32; off > 0; off >>= 1) m = fmaxf(m, __shfl_xor(m, off));
    float e = act ? expf(acc - m) : 0.f;
#pragma unroll
    for (int off = 32; off > 0; off >>= 1) e += __shfl_xor(e, off);
    const float lse = m + logf(e);
    if (act) out[node * NCLS + lane] = acc - lse;
}

extern "C" void kernel_launch(void* const* d_in, const int* in_sizes, int n_in,
                              void* d_out, int out_size, void* d_ws, size_t ws_size,
                              hipStream_t stream) {
    const float* x   = (const float*)d_in[0];
    const int*   ei  = (const int*)d_in[1];
    const float* W1  = (const float*)d_in[2];
    const float* b1  = (const float*)d_in[3];
    const float* g1  = (const float*)d_in[4];
    const float* be1 = (const float*)d_in[5];
    const float* W2  = (const float*)d_in[6];
    const float* b2  = (const float*)d_in[7];
    const float* g2  = (const float*)d_in[8];
    const float* be2 = (const float*)d_in[9];
    const float* W3  = (const float*)d_in[10];
    const float* b3  = (const float*)d_in[11];
    float* out = (float*)d_out;

    const int* e_src = ei;
    const int* e_dst = ei + N_EDGES;

    // ---- workspace layout ----
    char* w = (char*)d_ws;
    _Float16* Xh  = (_Float16*)w;              w += (size_t)N_NODES * IN_FEAT * 2;  // 12.8 MB
    _Float16* H1h = (_Float16*)w;              w += (size_t)N_NODES * HIDDEN * 2;   // 25.6 MB
    _Float16* H2h = (_Float16*)w;              w += (size_t)N_NODES * HIDDEN * 2;   // 25.6 MB
    _Float16* XW3h = (_Float16*)w;             w += (size_t)N_NODES * NCLS * 2;     // 4 MB
    float* dinv   = (float*)w;                 w += (size_t)N_NODES * 4;
    int2*  edat   = (int2*)w;                  w += (size_t)N_EDGES * 8;            // 2.56 MB
    // --- contiguous zero-init region (single memset) ---
    int*   counts = (int*)w;                   w += (size_t)N_NODES * 4;            // 200000 B
    float* bnp2a  = (float*)w;                 w += (size_t)32 * 512 * 4;           // 64 KB
    float* bnp2b  = (float*)w;                 w += (size_t)32 * 512 * 4;           // 64 KB
    // ---
    int*   rowp   = (int*)w;                   w += (size_t)(N_NODES + 4) * 4;
    int*   cursor = (int*)w;                   w += (size_t)N_NODES * 4;
    int*   partials=(int*)w;                   w += 256 * 4;
    float* scale1 = (float*)w;                 w += 256 * 4;
    float* shift1 = (float*)w;                 w += 256 * 4;
    float* scale2 = (float*)w;                 w += 256 * 4;
    float* shift2 = (float*)w;                 w += 256 * 4;
    _Float16* W1p = (_Float16*)w;              w += (size_t)16 * 4 * 64 * 8 * 2;    // 64 KB
    _Float16* W2p = (_Float16*)w;              w += (size_t)16 * 8 * 64 * 8 * 2;    // 128 KB
    _Float16* W3p = (_Float16*)w;              w += (size_t)3 * 8 * 64 * 8 * 2;     // 24 KB

    const int EB = (N_EDGES + 255) / 256;

    // ---- CSR build + prep (hist fused with cast/pack) ----
    hipMemsetAsync(counts, 0, (size_t)N_NODES * 4 + 2 * (size_t)32 * 512 * 4, stream);
    k_prep<<<PREP_HIST_NB + PREP_CVT_NB + PREP_PACK_NB, 256, 0, stream>>>(
        e_dst, counts, x, Xh, W1, W2, W3, W1p, W2p, W3p);
    k_scan_local<<<SCAN_NB, SCAN_B, 0, stream>>>(counts, rowp, partials);
    k_scan_add<<<SCAN_NB, SCAN_B, 0, stream>>>(rowp, cursor, partials, counts, dinv);
    k_scatter<<<EB, 256, 0, stream>>>(e_src, e_dst, cursor, dinv, edat);

    // ---- layer 1: fused (gather X -> MFMA W1 + b1 -> H1h, stats) ----
    k_fused<IN_FEAT><<<GNB, 256, 0, stream>>>(
        Xh, rowp, edat, dinv, W1p, b1, H1h, bnp2a);
    k_bnprep<<<1, 256, 0, stream>>>(bnp2a, g1, be1, scale1, shift1);
    k_bnapply<<<BNA_NB, 256, 0, stream>>>(H1h, scale1, shift1);

    // ---- layer 2: fused (gather H1' -> MFMA W2 + b2 -> H2h, stats) ----
    k_fused<HIDDEN><<<GNB, 256, 0, stream>>>(
        H1h, rowp, edat, dinv, W2p, b2, H2h, bnp2b);
    k_bnprep<<<1, 256, 0, stream>>>(bnp2b, g2, be2, scale2, shift2);

    // ---- output layer ----
    k_gemm3<HIDDEN><<<GNB, 64, 0, stream>>>(H2h, W3p, scale2, shift2, XW3h);
    k_out<<<N_NODES / 4, 256, 0, stream>>>(XW3h, rowp, edat, dinv, b3, out);
}